// Round 16
// baseline (366.653 us; speedup 1.0000x reference)
//
#include <hip/hip_runtime.h>
#include <hip/hip_bf16.h>

// GraphConvNet: embed -> 2x[ MLP(2x 128x128, relu) -> sym-norm gather/scatter
// aggregation -> skip -> LayerNorm ] -> segment-mean pool -> decode.
// R2: bf16 MFMA matmuls (W split hi+lo bf16). R5: atomic-free graph prep.
// R8: bf16 residual. R9: embed+MLP fusion. R12: fused pool. R14: fp8 gather
// table (agg FETCH 206->105MB). R12/R13/R15: agg reshape A/Bs all neutral ->
// agg ~58us is the L2-miss/random-fill floor at this table size.
// R16: rank-augmented CSR fill — hist2's LDS atomicAdd old-value IS the
// edge's rank within its (slice, receiver) bucket; store it (u16, 3.2MB) and
// fill becomes ONE pass, no re-reads / LDS / atomics (old fill read each edge
// array 4x + 12.8MB pr16 via 100KB LDS preload).

#define N_NODES 100000
#define N_EDGES 1600000
#define N_GRAPH 100
#define NPG     1000
#define LATENT  128

#define NPART   4
#define PSIZE   (N_NODES / NPART)     // 25000 nodes per range
#define NSLICE  64
#define ESLICE  (N_EDGES / NSLICE)    // 25000 edges per slice

#define SCAN_CHUNK 2048
#define SCAN_NB    ((N_NODES + SCAN_CHUNK - 1) / SCAN_CHUNK)   // 49

typedef __attribute__((ext_vector_type(8))) short short8;
typedef __attribute__((ext_vector_type(4))) float f32x4;

__device__ __forceinline__ unsigned short f2bf(float f) {
    union { float f; unsigned int u; } v; v.f = f;
    unsigned int r = v.u + 0x7fff + ((v.u >> 16) & 1);   // RTNE
    return (unsigned short)(r >> 16);
}
__device__ __forceinline__ float bf2f(unsigned short u) {
    union { unsigned int u; float f; } v; v.u = ((unsigned int)u) << 16;
    return v.f;
}
// pack 4 floats -> 4 fp8 e4m3 bytes (HW cvt, RTNE)
__device__ __forceinline__ unsigned int pk_fp8x4(float a, float b, float c, float d) {
    int v = 0;
    v = __builtin_amdgcn_cvt_pk_fp8_f32(a, b, v, false);
    v = __builtin_amdgcn_cvt_pk_fp8_f32(c, d, v, true);
    return (unsigned int)v;
}

// ---------- dual LDS histogram + per-edge receiver rank ----------------------
__global__ __launch_bounds__(1024) void k_hist2(const int* __restrict__ senders,
                                                const int* __restrict__ receivers,
                                                unsigned short* __restrict__ ps16,
                                                unsigned short* __restrict__ pr16,
                                                unsigned short* __restrict__ rank) {
    __shared__ unsigned int cs[PSIZE / 2];         // 50 KB
    __shared__ unsigned int cr[PSIZE / 2];         // 50 KB
    int rg = blockIdx.x & (NPART - 1), sl = blockIdx.x >> 2;
    int lo = rg * PSIZE;
    for (int i = threadIdx.x; i < PSIZE / 2; i += 1024) { cs[i] = 0; cr[i] = 0; }
    __syncthreads();
    int e0 = sl * ESLICE;
    for (int e = e0 + threadIdx.x; e < e0 + ESLICE; e += 1024) {
        int s = senders[e] - lo;
        if ((unsigned)s < PSIZE) atomicAdd(&cs[s >> 1], 1u << ((s & 1) * 16));
        int r = receivers[e] - lo;
        if ((unsigned)r < PSIZE) {
            unsigned int old = atomicAdd(&cr[r >> 1], 1u << ((r & 1) * 16));
            rank[e] = (unsigned short)((old >> ((r & 1) * 16)) & 0xffff);
        }
    }
    __syncthreads();
    size_t base = (size_t)(rg * NSLICE + sl) * PSIZE;
    for (int i = threadIdx.x; i < PSIZE; i += 1024) {
        ps16[base + i] = (unsigned short)((cs[i >> 1] >> ((i & 1) * 16)) & 0xffff);
        pr16[base + i] = (unsigned short)((cr[i >> 1] >> ((i & 1) * 16)) & 0xffff);
    }
}

// ---------- per-node scan over slices; also block-reduces deg -> blocksums ---
__global__ __launch_bounds__(256) void k_scan_slices(const unsigned short* __restrict__ ps16,
                                                     unsigned short* __restrict__ pr16,
                                                     int* __restrict__ deg_r,
                                                     float* __restrict__ inv_s,
                                                     float* __restrict__ inv_r,
                                                     int* __restrict__ blocksums) {
    int t = threadIdx.x;
    int n = blockIdx.x * 256 + t;
    int run = 0, ss = 0;
    if (n < N_NODES) {
        int rg = n / PSIZE, i = n - rg * PSIZE;
        size_t base = (size_t)rg * NSLICE * PSIZE + i;
#pragma unroll 4
        for (int sl = 0; sl < NSLICE; sl++) {
            size_t idx = base + (size_t)sl * PSIZE;
            int v = pr16[idx];
            pr16[idx] = (unsigned short)run;   // exclusive prefix over slices (local)
            run += v;
            ss += ps16[idx];
        }
        deg_r[n] = run;
        inv_r[n] = rsqrtf((float)(run + 1));   // +1 self loop
        inv_s[n] = rsqrtf((float)(ss + 1));
    }
    __shared__ int wsum[4];
    int s = run;
#pragma unroll
    for (int off = 32; off > 0; off >>= 1) s += __shfl_down(s, off, 64);
    if ((t & 63) == 0) wsum[t >> 6] = s;
    __syncthreads();
    if (t == 0)
        atomicAdd(&blocksums[blockIdx.x >> 3], wsum[0] + wsum[1] + wsum[2] + wsum[3]);
}

// ---------- apply: block offset computed in-kernel from raw blocksums --------
__global__ __launch_bounds__(256) void k_scan_apply(const int* __restrict__ deg,
                                                    const int* __restrict__ blocksums,
                                                    int* __restrict__ row_start, int n) {
    __shared__ int boff_s;
    int b = blockIdx.x, t = threadIdx.x;
    if (t < 64) {
        int v = (t < b && t < SCAN_NB) ? blocksums[t] : 0;
#pragma unroll
        for (int off = 32; off > 0; off >>= 1) v += __shfl_down(v, off, 64);
        if (t == 0) boff_s = v;
    }
    int base = b * SCAN_CHUNK + t * 8;
    int v[8]; int tsum = 0;
#pragma unroll
    for (int j = 0; j < 8; j++) { int i = base + j; v[j] = (i < n) ? deg[i] : 0; tsum += v[j]; }
    __shared__ int wtot[4];
    int inc = tsum;
#pragma unroll
    for (int off = 1; off < 64; off <<= 1) {
        int u = __shfl_up(inc, off, 64);
        if ((t & 63) >= off) inc += u;
    }
    if ((t & 63) == 63) wtot[t >> 6] = inc;
    __syncthreads();
    int wbase = 0;
    for (int w = 0; w < (t >> 6); w++) wbase += wtot[w];
    int running = boff_s + wbase + (inc - tsum);
#pragma unroll
    for (int j = 0; j < 8; j++) {
        int i = base + j;
        if (i < n) {
            row_start[i] = running;
            running += v[j];
            if (i == n - 1) row_start[n] = running;
        }
    }
}

// ---------- single-pass CSR fill using precomputed ranks ---------------------
// pos = row_start[r] + slice-local-prefix + in-slice rank. No atomics, no LDS.
__global__ __launch_bounds__(256) void k_fill3(const int* __restrict__ senders,
                                               const int* __restrict__ receivers,
                                               const unsigned short* __restrict__ rank,
                                               const unsigned short* __restrict__ pr16,
                                               const int* __restrict__ row_start,
                                               int* __restrict__ edge_src) {
    int e = blockIdx.x * 256 + threadIdx.x;
    if (e >= N_EDGES) return;
    int r = receivers[e];
    int sl = e / ESLICE;
    int rg = r / PSIZE;
    int i = r - rg * PSIZE;
    int off = pr16[(size_t)(rg * NSLICE + sl) * PSIZE + i];
    edge_src[row_start[r] + off + (int)rank[e]] = senders[e];
}

// ---------- weight prep: pack bf16 hi/lo fragments in MFMA B-operand order ----
__global__ void k_wprep(const float* __restrict__ embed_w, const float* __restrict__ mlp_w,
                        unsigned short* __restrict__ hi, unsigned short* __restrict__ lo) {
    int t = blockIdx.x * 256 + threadIdx.x;
    if (t >= 8192 + 4 * 16384) return;
    const float* src; int local;
    if (t < 8192) { src = embed_w; local = t; }
    else { int m = t - 8192; src = mlp_w + (size_t)(m >> 14) * 16384; local = m & 16383; }
    int j = local & 7, lane = (local >> 3) & 63, tn = (local >> 9) & 7, kc = local >> 12;
    int k = kc * 32 + ((lane >> 4) << 3) + j;
    int n = tn * 16 + (lane & 15);
    float wv = src[k * 128 + n];
    unsigned short h = f2bf(wv);
    float rem = wv - bf2f(h);
    hi[t] = h; lo[t] = f2bf(rem);
}

// ---------- fused embed + MLP step 0 (x out: fp8) ----------------------------
__global__ __launch_bounds__(256) void k_embed_mlp(
    const float* __restrict__ A,
    const unsigned short* __restrict__ wehi, const unsigned short* __restrict__ welo,
    const float* __restrict__ eb,
    const unsigned short* __restrict__ w0hi, const unsigned short* __restrict__ w0lo,
    const unsigned short* __restrict__ w1hi, const unsigned short* __restrict__ w1lo,
    const float* __restrict__ b0, const float* __restrict__ b1,
    const float* __restrict__ inv_s,
    unsigned short* __restrict__ h16, unsigned char* __restrict__ x8, int M)
{
    __shared__ __align__(16) unsigned short t0[4][32][136];   // per-wave
    int t = threadIdx.x, w = t >> 6, L = t & 63;
    int m0 = blockIdx.x * 128 + w * 32;
    int lr = L & 15, lk = (L >> 4) * 8, lq = (L >> 4) * 4;

    float ebv[8], b0v[8], b1v[8];
#pragma unroll
    for (int tn = 0; tn < 8; tn++) {
        ebv[tn] = eb[tn * 16 + lr];
        b0v[tn] = b0[tn * 16 + lr];
        b1v[tn] = b1[tn * 16 + lr];
    }

    // ---- embed: nodes (fp32, K=64) @ We ----
    f32x4 acc[2][8];
#pragma unroll
    for (int bd = 0; bd < 2; bd++)
#pragma unroll
        for (int tn = 0; tn < 8; tn++) acc[bd][tn] = (f32x4){0.f, 0.f, 0.f, 0.f};
#pragma unroll
    for (int kc = 0; kc < 2; kc++) {
        short8 a[2];
#pragma unroll
        for (int bd = 0; bd < 2; bd++) {
            int grow = m0 + bd * 16 + lr; if (grow >= M) grow = M - 1;
            const float* rp = A + (size_t)grow * 64 + kc * 32 + lk;
            float4 v0 = *(const float4*)rp;
            float4 v1 = *(const float4*)(rp + 4);
            short8 pk;
            pk[0] = (short)f2bf(v0.x); pk[1] = (short)f2bf(v0.y);
            pk[2] = (short)f2bf(v0.z); pk[3] = (short)f2bf(v0.w);
            pk[4] = (short)f2bf(v1.x); pk[5] = (short)f2bf(v1.y);
            pk[6] = (short)f2bf(v1.z); pk[7] = (short)f2bf(v1.w);
            a[bd] = pk;
        }
#pragma unroll
        for (int tn = 0; tn < 8; tn++) {
            size_t fo = (size_t)(((kc * 8 + tn) * 64 + L)) * 8;
            short8 bh = *(const short8*)(wehi + fo);
            short8 bl = *(const short8*)(welo + fo);
#pragma unroll
            for (int bd = 0; bd < 2; bd++) {
                acc[bd][tn] = __builtin_amdgcn_mfma_f32_16x16x32_bf16(a[bd], bh, acc[bd][tn], 0, 0, 0);
                acc[bd][tn] = __builtin_amdgcn_mfma_f32_16x16x32_bf16(a[bd], bl, acc[bd][tn], 0, 0, 0);
            }
        }
    }
#pragma unroll
    for (int bd = 0; bd < 2; bd++)
#pragma unroll
        for (int tn = 0; tn < 8; tn++)
#pragma unroll
            for (int r = 0; r < 4; r++)
                t0[w][bd * 16 + lq + r][tn * 16 + lr] = f2bf(acc[bd][tn][r] + ebv[tn]);
#pragma unroll
    for (int q = 0; q < 8; q++) {
        int s = q * 64 + L;
        int row = s >> 4, c0 = (s & 15) * 8;
        int grow = m0 + row;
        if (grow < M)
            *(short8*)(h16 + (size_t)grow * 128 + c0) = *(const short8*)&t0[w][row][c0];
    }

    // ---- layer 1: t0 @ W0 ----
#pragma unroll
    for (int bd = 0; bd < 2; bd++)
#pragma unroll
        for (int tn = 0; tn < 8; tn++) acc[bd][tn] = (f32x4){0.f, 0.f, 0.f, 0.f};
#pragma unroll
    for (int kc = 0; kc < 4; kc++) {
        short8 a[2];
#pragma unroll
        for (int bd = 0; bd < 2; bd++)
            a[bd] = *(const short8*)&t0[w][bd * 16 + lr][kc * 32 + lk];
#pragma unroll
        for (int tn = 0; tn < 8; tn++) {
            size_t fo = (size_t)(((kc * 8 + tn) * 64 + L)) * 8;
            short8 bh = *(const short8*)(w0hi + fo);
            short8 bl = *(const short8*)(w0lo + fo);
#pragma unroll
            for (int bd = 0; bd < 2; bd++) {
                acc[bd][tn] = __builtin_amdgcn_mfma_f32_16x16x32_bf16(a[bd], bh, acc[bd][tn], 0, 0, 0);
                acc[bd][tn] = __builtin_amdgcn_mfma_f32_16x16x32_bf16(a[bd], bl, acc[bd][tn], 0, 0, 0);
            }
        }
    }
#pragma unroll
    for (int bd = 0; bd < 2; bd++)
#pragma unroll
        for (int tn = 0; tn < 8; tn++)
#pragma unroll
            for (int r = 0; r < 4; r++)
                t0[w][bd * 16 + lq + r][tn * 16 + lr] = f2bf(fmaxf(acc[bd][tn][r] + b0v[tn], 0.f));

    // ---- layer 2: t0 @ W1 ----
#pragma unroll
    for (int bd = 0; bd < 2; bd++)
#pragma unroll
        for (int tn = 0; tn < 8; tn++) acc[bd][tn] = (f32x4){0.f, 0.f, 0.f, 0.f};
#pragma unroll
    for (int kc = 0; kc < 4; kc++) {
        short8 a[2];
#pragma unroll
        for (int bd = 0; bd < 2; bd++)
            a[bd] = *(const short8*)&t0[w][bd * 16 + lr][kc * 32 + lk];
#pragma unroll
        for (int tn = 0; tn < 8; tn++) {
            size_t fo = (size_t)(((kc * 8 + tn) * 64 + L)) * 8;
            short8 bh = *(const short8*)(w1hi + fo);
            short8 bl = *(const short8*)(w1lo + fo);
#pragma unroll
            for (int bd = 0; bd < 2; bd++) {
                acc[bd][tn] = __builtin_amdgcn_mfma_f32_16x16x32_bf16(a[bd], bh, acc[bd][tn], 0, 0, 0);
                acc[bd][tn] = __builtin_amdgcn_mfma_f32_16x16x32_bf16(a[bd], bl, acc[bd][tn], 0, 0, 0);
            }
        }
    }
    float invs[2][4];
#pragma unroll
    for (int bd = 0; bd < 2; bd++)
#pragma unroll
        for (int r = 0; r < 4; r++) {
            int grow = m0 + bd * 16 + lq + r; if (grow >= M) grow = M - 1;
            invs[bd][r] = inv_s[grow];
        }
#pragma unroll
    for (int bd = 0; bd < 2; bd++)
#pragma unroll
        for (int tn = 0; tn < 8; tn++)
#pragma unroll
            for (int r = 0; r < 4; r++)
                t0[w][bd * 16 + lq + r][tn * 16 + lr] =
                    f2bf(fmaxf(acc[bd][tn][r] + b1v[tn], 0.f) * invs[bd][r]);
    // X -> fp8 store (8 channels = 8 B per lane-chunk, coalesced)
#pragma unroll
    for (int q = 0; q < 8; q++) {
        int s = q * 64 + L;
        int row = s >> 4, c0 = (s & 15) * 8;
        int grow = m0 + row;
        if (grow < M) {
            const unsigned short* sp = &t0[w][row][c0];
            uint2 v;
            v.x = pk_fp8x4(bf2f(sp[0]), bf2f(sp[1]), bf2f(sp[2]), bf2f(sp[3]));
            v.y = pk_fp8x4(bf2f(sp[4]), bf2f(sp[5]), bf2f(sp[6]), bf2f(sp[7]));
            *(uint2*)(x8 + (size_t)grow * 128 + c0) = v;
        }
    }
}

// ---------- MLP step 1 (reads h16 bf16 global; x out: fp8) -------------------
__global__ __launch_bounds__(256) void k_mlp(
    const unsigned short* __restrict__ A16, const unsigned short* __restrict__ w0hi,
    const unsigned short* __restrict__ w0lo, const unsigned short* __restrict__ w1hi,
    const unsigned short* __restrict__ w1lo, const float* __restrict__ b0,
    const float* __restrict__ b1, const float* __restrict__ inv_s,
    unsigned char* __restrict__ x8, int M)
{
    __shared__ __align__(16) unsigned short t1[4][32][136];   // per-wave, barrier-free
    int t = threadIdx.x, w = t >> 6, L = t & 63;
    int m0 = blockIdx.x * 128 + w * 32;
    int lr = L & 15, lk = (L >> 4) * 8, lq = (L >> 4) * 4;

    float b0v[8], b1v[8];
#pragma unroll
    for (int tn = 0; tn < 8; tn++) { b0v[tn] = b0[tn * 16 + lr]; b1v[tn] = b1[tn * 16 + lr]; }

    f32x4 acc[2][8];
#pragma unroll
    for (int bd = 0; bd < 2; bd++)
#pragma unroll
        for (int tn = 0; tn < 8; tn++) acc[bd][tn] = (f32x4){0.f, 0.f, 0.f, 0.f};

#pragma unroll
    for (int kc = 0; kc < 4; kc++) {
        short8 a[2];
#pragma unroll
        for (int bd = 0; bd < 2; bd++) {
            int grow = m0 + bd * 16 + lr; if (grow >= M) grow = M - 1;
            a[bd] = *(const short8*)(A16 + (size_t)grow * 128 + kc * 32 + lk);
        }
#pragma unroll
        for (int tn = 0; tn < 8; tn++) {
            size_t fo = (size_t)(((kc * 8 + tn) * 64 + L)) * 8;
            short8 bh = *(const short8*)(w0hi + fo);
            short8 bl = *(const short8*)(w0lo + fo);
#pragma unroll
            for (int bd = 0; bd < 2; bd++) {
                acc[bd][tn] = __builtin_amdgcn_mfma_f32_16x16x32_bf16(a[bd], bh, acc[bd][tn], 0, 0, 0);
                acc[bd][tn] = __builtin_amdgcn_mfma_f32_16x16x32_bf16(a[bd], bl, acc[bd][tn], 0, 0, 0);
            }
        }
    }
#pragma unroll
    for (int bd = 0; bd < 2; bd++)
#pragma unroll
        for (int tn = 0; tn < 8; tn++)
#pragma unroll
            for (int r = 0; r < 4; r++)
                t1[w][bd * 16 + lq + r][tn * 16 + lr] = f2bf(fmaxf(acc[bd][tn][r] + b0v[tn], 0.f));

    f32x4 acc2[2][8];
#pragma unroll
    for (int bd = 0; bd < 2; bd++)
#pragma unroll
        for (int tn = 0; tn < 8; tn++) acc2[bd][tn] = (f32x4){0.f, 0.f, 0.f, 0.f};
#pragma unroll
    for (int kc = 0; kc < 4; kc++) {
        short8 a[2];
#pragma unroll
        for (int bd = 0; bd < 2; bd++)
            a[bd] = *(const short8*)&t1[w][bd * 16 + lr][kc * 32 + lk];
#pragma unroll
        for (int tn = 0; tn < 8; tn++) {
            size_t fo = (size_t)(((kc * 8 + tn) * 64 + L)) * 8;
            short8 bh = *(const short8*)(w1hi + fo);
            short8 bl = *(const short8*)(w1lo + fo);
#pragma unroll
            for (int bd = 0; bd < 2; bd++) {
                acc2[bd][tn] = __builtin_amdgcn_mfma_f32_16x16x32_bf16(a[bd], bh, acc2[bd][tn], 0, 0, 0);
                acc2[bd][tn] = __builtin_amdgcn_mfma_f32_16x16x32_bf16(a[bd], bl, acc2[bd][tn], 0, 0, 0);
            }
        }
    }
    float invs[2][4];
#pragma unroll
    for (int bd = 0; bd < 2; bd++)
#pragma unroll
        for (int r = 0; r < 4; r++) {
            int grow = m0 + bd * 16 + lq + r; if (grow >= M) grow = M - 1;
            invs[bd][r] = inv_s[grow];
        }
#pragma unroll
    for (int bd = 0; bd < 2; bd++)
#pragma unroll
        for (int tn = 0; tn < 8; tn++)
#pragma unroll
            for (int r = 0; r < 4; r++)
                t1[w][bd * 16 + lq + r][tn * 16 + lr] =
                    f2bf(fmaxf(acc2[bd][tn][r] + b1v[tn], 0.f) * invs[bd][r]);
#pragma unroll
    for (int q = 0; q < 8; q++) {
        int s = q * 64 + L;
        int row = s >> 4, c0 = (s & 15) * 8;
        int grow = m0 + row;
        if (grow < M) {
            const unsigned short* sp = &t1[w][row][c0];
            uint2 v;
            v.x = pk_fp8x4(bf2f(sp[0]), bf2f(sp[1]), bf2f(sp[2]), bf2f(sp[3]));
            v.y = pk_fp8x4(bf2f(sp[4]), bf2f(sp[5]), bf2f(sp[6]), bf2f(sp[7]));
            *(uint2*)(x8 + (size_t)grow * 128 + c0) = v;
        }
    }
}

// ---------- gather core (fp8 table): full batches + ONE masked batch ---------
__device__ __forceinline__ float2 agg_gather8(const unsigned char* __restrict__ x8,
                                              const int* __restrict__ edge_src,
                                              int node, int L, int beg, int end)
{
    unsigned short su = *(const unsigned short*)(x8 + (size_t)node * 128 + 2 * L);
    float2 acc;
    acc.x = __builtin_amdgcn_cvt_f32_fp8((int)su, 0);    // self loop
    acc.y = __builtin_amdgcn_cvt_f32_fp8((int)su, 1);

    int j = beg;
    for (; j + 8 <= end; j += 8) {
        unsigned short u[8];
#pragma unroll
        for (int q = 0; q < 8; q++)
            u[q] = *(const unsigned short*)(x8 + (size_t)edge_src[j + q] * 128 + 2 * L);
#pragma unroll
        for (int q = 0; q < 8; q++) {
            acc.x += __builtin_amdgcn_cvt_f32_fp8((int)u[q], 0);
            acc.y += __builtin_amdgcn_cvt_f32_fp8((int)u[q], 1);
        }
    }
    if (j < end) {                                  // masked parallel remainder
        int last = end - 1;
        unsigned short u[8];
#pragma unroll
        for (int q = 0; q < 8; q++) {
            int jj = j + q; if (jj > last) jj = last;
            u[q] = *(const unsigned short*)(x8 + (size_t)edge_src[jj] * 128 + 2 * L);
        }
#pragma unroll
        for (int q = 0; q < 8; q++) {
            float a = __builtin_amdgcn_cvt_f32_fp8((int)u[q], 0);
            float b = __builtin_amdgcn_cvt_f32_fp8((int)u[q], 1);
            if (j + q <= last) { acc.x += a; acc.y += b; }   // wave-uniform pred
        }
    }
    return acc;
}

// ---------- agg step 0: 1 wave/node, writes h16 ------------------------------
__global__ __launch_bounds__(256) void k_agg_ln(
    const unsigned char* __restrict__ x8, const int* __restrict__ row_start,
    const int* __restrict__ edge_src, const float* __restrict__ inv_r,
    const float* __restrict__ ln_scale, const float* __restrict__ ln_offset,
    unsigned short* __restrict__ h16)
{
    int node = __builtin_amdgcn_readfirstlane(blockIdx.x * 4 + (threadIdx.x >> 6));
    int L = threadIdx.x & 63;
    const unsigned int* h32 = (const unsigned int*)h16;

    int beg = row_start[node], end = row_start[node + 1];
    float2 acc = agg_gather8(x8, edge_src, node, L, beg, end);

    float ir = inv_r[node];
    unsigned int hu = h32[(size_t)node * 64 + L];
    float y0 = acc.x * ir + __uint_as_float(hu << 16);
    float y1 = acc.y * ir + __uint_as_float(hu & 0xffff0000u);

    float s1 = y0 + y1, s2 = y0 * y0 + y1 * y1;
#pragma unroll
    for (int off = 32; off > 0; off >>= 1) {
        s1 += __shfl_xor(s1, off, 64);
        s2 += __shfl_xor(s2, off, 64);
    }
    float mu = s1 * (1.f / 128.f);
    float var = fmaxf(s2 * (1.f / 128.f) - mu * mu, 0.f);
    float rstd = rsqrtf(var + 1e-5f);
    float2 sc = *(const float2*)&ln_scale[L * 2];
    float2 of = *(const float2*)&ln_offset[L * 2];
    float ox = (y0 - mu) * rstd * sc.x + of.x;
    float oy = (y1 - mu) * rstd * sc.y + of.y;
    ((unsigned int*)h16)[(size_t)node * 64 + L] =
        (unsigned int)f2bf(ox) | ((unsigned int)f2bf(oy) << 16);
}

// ---------- agg step 1 + pooling: no h16 write -------------------------------
__global__ __launch_bounds__(256) void k_agg_pool(
    const unsigned char* __restrict__ x8, const int* __restrict__ row_start,
    const int* __restrict__ edge_src, const float* __restrict__ inv_r,
    const float* __restrict__ ln_scale, const float* __restrict__ ln_offset,
    const unsigned short* __restrict__ h16, float* __restrict__ poolpart)
{
    __shared__ float2 part[4][64];
    int w = threadIdx.x >> 6, L = threadIdx.x & 63;
    int node = __builtin_amdgcn_readfirstlane(blockIdx.x * 4 + w);
    const unsigned int* h32 = (const unsigned int*)h16;

    int beg = row_start[node], end = row_start[node + 1];
    float2 acc = agg_gather8(x8, edge_src, node, L, beg, end);

    float ir = inv_r[node];
    unsigned int hu = h32[(size_t)node * 64 + L];
    float y0 = acc.x * ir + __uint_as_float(hu << 16);
    float y1 = acc.y * ir + __uint_as_float(hu & 0xffff0000u);

    float s1 = y0 + y1, s2 = y0 * y0 + y1 * y1;
#pragma unroll
    for (int off = 32; off > 0; off >>= 1) {
        s1 += __shfl_xor(s1, off, 64);
        s2 += __shfl_xor(s2, off, 64);
    }
    float mu = s1 * (1.f / 128.f);
    float var = fmaxf(s2 * (1.f / 128.f) - mu * mu, 0.f);
    float rstd = rsqrtf(var + 1e-5f);
    float2 sc = *(const float2*)&ln_scale[L * 2];
    float2 of = *(const float2*)&ln_offset[L * 2];
    float2 o;
    o.x = (y0 - mu) * rstd * sc.x + of.x;
    o.y = (y1 - mu) * rstd * sc.y + of.y;
    part[w][L] = o;
    __syncthreads();
    if (w == 0) {
        float2 p0 = part[0][L], p1 = part[1][L], p2 = part[2][L], p3 = part[3][L];
        float2 s;
        s.x = (p0.x + p1.x) + (p2.x + p3.x);
        s.y = (p0.y + p1.y) + (p2.y + p3.y);
        *(float2*)&poolpart[(size_t)blockIdx.x * 128 + L * 2] = s;
    }
}

// ---------- pool reduce level 1: 25000 partial rows -> 1000 ----------
__global__ __launch_bounds__(128) void k_pool2(const float* __restrict__ poolpart,
                                               float* __restrict__ poolpart2) {
    int b = blockIdx.x, col = threadIdx.x;
    const float* pg = poolpart + ((size_t)b * 25) * 128;
    float s = 0.f;
#pragma unroll
    for (int k = 0; k < 25; k++) s += pg[k * 128 + col];
    poolpart2[(size_t)b * 128 + col] = s;
}

// ---------- pool reduce level 2 + decode ----------
__global__ __launch_bounds__(128) void k_pool3(const float* __restrict__ poolpart2,
                                               const float* __restrict__ dec_w,
                                               const float* __restrict__ dec_b,
                                               float* __restrict__ out) {
    int g = blockIdx.x, col = threadIdx.x;
    const float* pg = poolpart2 + (size_t)g * 10 * 128;
    float s = 0.f;
#pragma unroll
    for (int c = 0; c < 10; c++) s += pg[c * 128 + col];
    s = s * (1.f / (float)NPG) * dec_w[col];
    __shared__ float ws[2];
#pragma unroll
    for (int off = 32; off > 0; off >>= 1) s += __shfl_down(s, off, 64);
    if ((col & 63) == 0) ws[col >> 6] = s;
    __syncthreads();
    if (col == 0) out[g] = ws[0] + ws[1] + dec_b[0];
}

extern "C" void kernel_launch(void* const* d_in, const int* in_sizes, int n_in,
                              void* d_out, int out_size, void* d_ws, size_t ws_size,
                              hipStream_t stream) {
    (void)in_sizes; (void)n_in; (void)out_size; (void)ws_size;
    const float* nodes     = (const float*)d_in[0];
    const int*   senders   = (const int*)d_in[1];
    const int*   receivers = (const int*)d_in[2];
    const float* embed_w   = (const float*)d_in[4];
    const float* embed_b   = (const float*)d_in[5];
    const float* mlp_w     = (const float*)d_in[6];
    const float* mlp_b     = (const float*)d_in[7];
    const float* ln_scale  = (const float*)d_in[8];
    const float* ln_offset = (const float*)d_in[9];
    const float* dec_w     = (const float*)d_in[10];
    const float* dec_b     = (const float*)d_in[11];
    float* out = (float*)d_out;

    const int N = N_NODES;
    const int WF_TOTAL = 8192 + 4 * 16384;          // frag elements (shorts)
    const size_t PART_TOTAL = (size_t)NPART * NSLICE * PSIZE;  // 6.4M entries

    char* p = (char*)d_ws;
    auto alloc = [&](size_t bytes) -> void* {
        void* r = (void*)p;
        p += (bytes + 255) & ~(size_t)255;
        return r;
    };
    unsigned short* h16      = (unsigned short*)alloc((size_t)N * 128 * 2);
    unsigned char*  x8       = (unsigned char*)alloc((size_t)N * 128);
    int*            edge_src = (int*)alloc((size_t)N_EDGES * 4);
    unsigned short* rank     = (unsigned short*)alloc((size_t)N_EDGES * 2);
    unsigned short* ps16     = (unsigned short*)alloc(PART_TOTAL * 2);
    unsigned short* pr16     = (unsigned short*)alloc(PART_TOTAL * 2);
    int*            deg_r    = (int*)alloc((size_t)N * 4);
    float*          inv_s    = (float*)alloc((size_t)N * 4);
    float*          inv_r    = (float*)alloc((size_t)N * 4);
    int*            row_start= (int*)alloc((size_t)(N + 1) * 4);
    int*            blocksums= (int*)alloc((size_t)SCAN_NB * 4);
    unsigned short* wfhi     = (unsigned short*)alloc((size_t)WF_TOTAL * 2);
    unsigned short* wflo     = (unsigned short*)alloc((size_t)WF_TOTAL * 2);
    float*          poolpart = (float*)alloc((size_t)(N / 4) * 128 * 4);
    float*          poolpart2= (float*)alloc((size_t)1000 * 128 * 4);

    hipMemsetAsync(blocksums, 0, (size_t)SCAN_NB * 4, stream);
    k_wprep<<<(WF_TOTAL + 255) / 256, 256, 0, stream>>>(embed_w, mlp_w, wfhi, wflo);

    // graph prep — no global fp32 atomics (391 int atomics for blocksums only)
    k_hist2<<<NPART * NSLICE, 1024, 0, stream>>>(senders, receivers, ps16, pr16, rank);
    k_scan_slices<<<(N + 255) / 256, 256, 0, stream>>>(ps16, pr16, deg_r, inv_s, inv_r, blocksums);
    k_scan_apply<<<SCAN_NB, 256, 0, stream>>>(deg_r, blocksums, row_start, N);
    k_fill3<<<(N_EDGES + 255) / 256, 256, 0, stream>>>(senders, receivers, rank, pr16,
                                                       row_start, edge_src);

    int mblocks = (N + 127) / 128;
    const unsigned short* wehi = wfhi, *welo = wflo;
    const unsigned short* w0hi[2] = { wfhi + 8192,             wfhi + 8192 + 2 * 16384 };
    const unsigned short* w0lo[2] = { wflo + 8192,             wflo + 8192 + 2 * 16384 };
    const unsigned short* w1hi[2] = { wfhi + 8192 + 16384,     wfhi + 8192 + 3 * 16384 };
    const unsigned short* w1lo[2] = { wflo + 8192 + 16384,     wflo + 8192 + 3 * 16384 };

    // step 0: fused embed + MLP, then agg+LN into h16
    k_embed_mlp<<<mblocks, 256, 0, stream>>>(nodes, wehi, welo, embed_b,
                                             w0hi[0], w0lo[0], w1hi[0], w1lo[0],
                                             mlp_b, mlp_b + 128, inv_s, h16, x8, N);
    k_agg_ln<<<N / 4, 256, 0, stream>>>(x8, row_start, edge_src, inv_r,
                                        ln_scale, ln_offset, h16);
    // step 1: MLP, then agg+LN fused with pooling (no h16 write)
    k_mlp<<<mblocks, 256, 0, stream>>>(h16, w0hi[1], w0lo[1], w1hi[1], w1lo[1],
                                       mlp_b + 256, mlp_b + 384, inv_s, x8, N);
    k_agg_pool<<<N / 4, 256, 0, stream>>>(x8, row_start, edge_src, inv_r,
                                          ln_scale + 128, ln_offset + 128, h16, poolpart);

    k_pool2<<<1000, 128, 0, stream>>>(poolpart, poolpart2);
    k_pool3<<<N_GRAPH, 128, 0, stream>>>(poolpart2, dec_w, dec_b, out);
}

// Round 17
// 355.007 us; speedup vs baseline: 1.0328x; 1.0328x over previous
//
#include <hip/hip_runtime.h>
#include <hip/hip_bf16.h>

// GraphConvNet: embed -> 2x[ MLP(2x 128x128, relu) -> sym-norm gather/scatter
// aggregation -> skip -> LayerNorm ] -> segment-mean pool -> decode.
// R2: bf16 MFMA matmuls (W split hi+lo bf16). R5: atomic-free graph prep.
// R8: bf16 residual. R9: embed+MLP fusion. R12: fused pool. R14: fp8 gather
// table (agg FETCH 206->105MB). Agg A/Bs (R12 batch depth, R13 request shape,
// R15 masked tail) all neutral -> agg ~58us = L2 random-fill floor at 12.8MB
// table. R16 FAILED (+11us): rank-fill swapped coalesced edge re-reads for a
// RANDOM 2B gather into 12.8MB pr16 (64B line per 2B used) — reverted.
// R17 = R15 verbatim (best known, 355us).

#define N_NODES 100000
#define N_EDGES 1600000
#define N_GRAPH 100
#define NPG     1000
#define LATENT  128

#define NPART   4
#define PSIZE   (N_NODES / NPART)     // 25000 nodes per range
#define NSLICE  64
#define ESLICE  (N_EDGES / NSLICE)    // 25000 edges per slice

#define SCAN_CHUNK 2048
#define SCAN_NB    ((N_NODES + SCAN_CHUNK - 1) / SCAN_CHUNK)   // 49

typedef __attribute__((ext_vector_type(8))) short short8;
typedef __attribute__((ext_vector_type(4))) float f32x4;

__device__ __forceinline__ unsigned short f2bf(float f) {
    union { float f; unsigned int u; } v; v.f = f;
    unsigned int r = v.u + 0x7fff + ((v.u >> 16) & 1);   // RTNE
    return (unsigned short)(r >> 16);
}
__device__ __forceinline__ float bf2f(unsigned short u) {
    union { unsigned int u; float f; } v; v.u = ((unsigned int)u) << 16;
    return v.f;
}
// pack 4 floats -> 4 fp8 e4m3 bytes (HW cvt, RTNE)
__device__ __forceinline__ unsigned int pk_fp8x4(float a, float b, float c, float d) {
    int v = 0;
    v = __builtin_amdgcn_cvt_pk_fp8_f32(a, b, v, false);
    v = __builtin_amdgcn_cvt_pk_fp8_f32(c, d, v, true);
    return (unsigned int)v;
}

// ---------- dual LDS histogram, packed u16 counters (NPART=4) ----------------
__global__ __launch_bounds__(1024) void k_hist2(const int* __restrict__ senders,
                                                const int* __restrict__ receivers,
                                                unsigned short* __restrict__ ps16,
                                                unsigned short* __restrict__ pr16) {
    __shared__ unsigned int cs[PSIZE / 2];         // 50 KB
    __shared__ unsigned int cr[PSIZE / 2];         // 50 KB
    int rg = blockIdx.x & (NPART - 1), sl = blockIdx.x >> 2;
    int lo = rg * PSIZE;
    for (int i = threadIdx.x; i < PSIZE / 2; i += 1024) { cs[i] = 0; cr[i] = 0; }
    __syncthreads();
    int e0 = sl * ESLICE;
    for (int e = e0 + threadIdx.x; e < e0 + ESLICE; e += 1024) {
        int s = senders[e] - lo;
        if ((unsigned)s < PSIZE) atomicAdd(&cs[s >> 1], 1u << ((s & 1) * 16));
        int r = receivers[e] - lo;
        if ((unsigned)r < PSIZE) atomicAdd(&cr[r >> 1], 1u << ((r & 1) * 16));
    }
    __syncthreads();
    size_t base = (size_t)(rg * NSLICE + sl) * PSIZE;
    for (int i = threadIdx.x; i < PSIZE; i += 1024) {
        ps16[base + i] = (unsigned short)((cs[i >> 1] >> ((i & 1) * 16)) & 0xffff);
        pr16[base + i] = (unsigned short)((cr[i >> 1] >> ((i & 1) * 16)) & 0xffff);
    }
}

// ---------- per-node scan over slices; also block-reduces deg -> blocksums ---
__global__ __launch_bounds__(256) void k_scan_slices(const unsigned short* __restrict__ ps16,
                                                     unsigned short* __restrict__ pr16,
                                                     int* __restrict__ deg_r,
                                                     float* __restrict__ inv_s,
                                                     float* __restrict__ inv_r,
                                                     int* __restrict__ blocksums) {
    int t = threadIdx.x;
    int n = blockIdx.x * 256 + t;
    int run = 0, ss = 0;
    if (n < N_NODES) {
        int rg = n / PSIZE, i = n - rg * PSIZE;
        size_t base = (size_t)rg * NSLICE * PSIZE + i;
#pragma unroll 4
        for (int sl = 0; sl < NSLICE; sl++) {
            size_t idx = base + (size_t)sl * PSIZE;
            int v = pr16[idx];
            pr16[idx] = (unsigned short)run;   // exclusive prefix over slices (local)
            run += v;
            ss += ps16[idx];
        }
        deg_r[n] = run;
        inv_r[n] = rsqrtf((float)(run + 1));   // +1 self loop
        inv_s[n] = rsqrtf((float)(ss + 1));
    }
    // block sum of run -> blocksums[chunk] (256-node block lies in one chunk)
    __shared__ int wsum[4];
    int s = run;
#pragma unroll
    for (int off = 32; off > 0; off >>= 1) s += __shfl_down(s, off, 64);
    if ((t & 63) == 0) wsum[t >> 6] = s;
    __syncthreads();
    if (t == 0)
        atomicAdd(&blocksums[blockIdx.x >> 3], wsum[0] + wsum[1] + wsum[2] + wsum[3]);
}

// ---------- apply: block offset computed in-kernel from raw blocksums --------
__global__ __launch_bounds__(256) void k_scan_apply(const int* __restrict__ deg,
                                                    const int* __restrict__ blocksums,
                                                    int* __restrict__ row_start, int n) {
    __shared__ int boff_s;
    int b = blockIdx.x, t = threadIdx.x;
    if (t < 64) {
        int v = (t < b && t < SCAN_NB) ? blocksums[t] : 0;
#pragma unroll
        for (int off = 32; off > 0; off >>= 1) v += __shfl_down(v, off, 64);
        if (t == 0) boff_s = v;
    }
    int base = b * SCAN_CHUNK + t * 8;
    int v[8]; int tsum = 0;
#pragma unroll
    for (int j = 0; j < 8; j++) { int i = base + j; v[j] = (i < n) ? deg[i] : 0; tsum += v[j]; }
    __shared__ int wtot[4];
    int inc = tsum;
#pragma unroll
    for (int off = 1; off < 64; off <<= 1) {
        int u = __shfl_up(inc, off, 64);
        if ((t & 63) >= off) inc += u;
    }
    if ((t & 63) == 63) wtot[t >> 6] = inc;
    __syncthreads();
    int wbase = 0;
    for (int w = 0; w < (t >> 6); w++) wbase += wtot[w];
    int running = boff_s + wbase + (inc - tsum);
#pragma unroll
    for (int j = 0; j < 8; j++) {
        int i = base + j;
        if (i < n) {
            row_start[i] = running;
            running += v[j];
            if (i == n - 1) row_start[n] = running;
        }
    }
}

// ---------- CSR fill: bs = row_start + slice-local offset ----------
__global__ __launch_bounds__(1024) void k_fill2(const int* __restrict__ senders,
                                                const int* __restrict__ receivers,
                                                const unsigned short* __restrict__ pr16,
                                                const int* __restrict__ row_start,
                                                int* __restrict__ edge_src) {
    __shared__ int bs[PSIZE];                      // 100 KB
    int rg = blockIdx.x & (NPART - 1), sl = blockIdx.x >> 2;
    int lo = rg * PSIZE;
    const unsigned short* base = pr16 + (size_t)(rg * NSLICE + sl) * PSIZE;
    for (int i = threadIdx.x; i < PSIZE; i += 1024)
        bs[i] = row_start[lo + i] + (int)base[i];
    __syncthreads();
    int e0 = sl * ESLICE;
    for (int e = e0 + threadIdx.x; e < e0 + ESLICE; e += 1024) {
        int r = receivers[e] - lo;
        if ((unsigned)r < PSIZE) {
            int pos = atomicAdd(&bs[r], 1);        // LDS atomic only
            edge_src[pos] = senders[e];
        }
    }
}

// ---------- weight prep: pack bf16 hi/lo fragments in MFMA B-operand order ----
__global__ void k_wprep(const float* __restrict__ embed_w, const float* __restrict__ mlp_w,
                        unsigned short* __restrict__ hi, unsigned short* __restrict__ lo) {
    int t = blockIdx.x * 256 + threadIdx.x;
    if (t >= 8192 + 4 * 16384) return;
    const float* src; int local;
    if (t < 8192) { src = embed_w; local = t; }
    else { int m = t - 8192; src = mlp_w + (size_t)(m >> 14) * 16384; local = m & 16383; }
    int j = local & 7, lane = (local >> 3) & 63, tn = (local >> 9) & 7, kc = local >> 12;
    int k = kc * 32 + ((lane >> 4) << 3) + j;
    int n = tn * 16 + (lane & 15);
    float wv = src[k * 128 + n];
    unsigned short h = f2bf(wv);
    float rem = wv - bf2f(h);
    hi[t] = h; lo[t] = f2bf(rem);
}

// ---------- fused embed + MLP step 0 (x out: fp8) ----------------------------
__global__ __launch_bounds__(256) void k_embed_mlp(
    const float* __restrict__ A,
    const unsigned short* __restrict__ wehi, const unsigned short* __restrict__ welo,
    const float* __restrict__ eb,
    const unsigned short* __restrict__ w0hi, const unsigned short* __restrict__ w0lo,
    const unsigned short* __restrict__ w1hi, const unsigned short* __restrict__ w1lo,
    const float* __restrict__ b0, const float* __restrict__ b1,
    const float* __restrict__ inv_s,
    unsigned short* __restrict__ h16, unsigned char* __restrict__ x8, int M)
{
    __shared__ __align__(16) unsigned short t0[4][32][136];   // per-wave
    int t = threadIdx.x, w = t >> 6, L = t & 63;
    int m0 = blockIdx.x * 128 + w * 32;
    int lr = L & 15, lk = (L >> 4) * 8, lq = (L >> 4) * 4;

    float ebv[8], b0v[8], b1v[8];
#pragma unroll
    for (int tn = 0; tn < 8; tn++) {
        ebv[tn] = eb[tn * 16 + lr];
        b0v[tn] = b0[tn * 16 + lr];
        b1v[tn] = b1[tn * 16 + lr];
    }

    // ---- embed: nodes (fp32, K=64) @ We ----
    f32x4 acc[2][8];
#pragma unroll
    for (int bd = 0; bd < 2; bd++)
#pragma unroll
        for (int tn = 0; tn < 8; tn++) acc[bd][tn] = (f32x4){0.f, 0.f, 0.f, 0.f};
#pragma unroll
    for (int kc = 0; kc < 2; kc++) {
        short8 a[2];
#pragma unroll
        for (int bd = 0; bd < 2; bd++) {
            int grow = m0 + bd * 16 + lr; if (grow >= M) grow = M - 1;
            const float* rp = A + (size_t)grow * 64 + kc * 32 + lk;
            float4 v0 = *(const float4*)rp;
            float4 v1 = *(const float4*)(rp + 4);
            short8 pk;
            pk[0] = (short)f2bf(v0.x); pk[1] = (short)f2bf(v0.y);
            pk[2] = (short)f2bf(v0.z); pk[3] = (short)f2bf(v0.w);
            pk[4] = (short)f2bf(v1.x); pk[5] = (short)f2bf(v1.y);
            pk[6] = (short)f2bf(v1.z); pk[7] = (short)f2bf(v1.w);
            a[bd] = pk;
        }
#pragma unroll
        for (int tn = 0; tn < 8; tn++) {
            size_t fo = (size_t)(((kc * 8 + tn) * 64 + L)) * 8;
            short8 bh = *(const short8*)(wehi + fo);
            short8 bl = *(const short8*)(welo + fo);
#pragma unroll
            for (int bd = 0; bd < 2; bd++) {
                acc[bd][tn] = __builtin_amdgcn_mfma_f32_16x16x32_bf16(a[bd], bh, acc[bd][tn], 0, 0, 0);
                acc[bd][tn] = __builtin_amdgcn_mfma_f32_16x16x32_bf16(a[bd], bl, acc[bd][tn], 0, 0, 0);
            }
        }
    }
#pragma unroll
    for (int bd = 0; bd < 2; bd++)
#pragma unroll
        for (int tn = 0; tn < 8; tn++)
#pragma unroll
            for (int r = 0; r < 4; r++)
                t0[w][bd * 16 + lq + r][tn * 16 + lr] = f2bf(acc[bd][tn][r] + ebv[tn]);
#pragma unroll
    for (int q = 0; q < 8; q++) {
        int s = q * 64 + L;
        int row = s >> 4, c0 = (s & 15) * 8;
        int grow = m0 + row;
        if (grow < M)
            *(short8*)(h16 + (size_t)grow * 128 + c0) = *(const short8*)&t0[w][row][c0];
    }

    // ---- layer 1: t0 @ W0 ----
#pragma unroll
    for (int bd = 0; bd < 2; bd++)
#pragma unroll
        for (int tn = 0; tn < 8; tn++) acc[bd][tn] = (f32x4){0.f, 0.f, 0.f, 0.f};
#pragma unroll
    for (int kc = 0; kc < 4; kc++) {
        short8 a[2];
#pragma unroll
        for (int bd = 0; bd < 2; bd++)
            a[bd] = *(const short8*)&t0[w][bd * 16 + lr][kc * 32 + lk];
#pragma unroll
        for (int tn = 0; tn < 8; tn++) {
            size_t fo = (size_t)(((kc * 8 + tn) * 64 + L)) * 8;
            short8 bh = *(const short8*)(w0hi + fo);
            short8 bl = *(const short8*)(w0lo + fo);
#pragma unroll
            for (int bd = 0; bd < 2; bd++) {
                acc[bd][tn] = __builtin_amdgcn_mfma_f32_16x16x32_bf16(a[bd], bh, acc[bd][tn], 0, 0, 0);
                acc[bd][tn] = __builtin_amdgcn_mfma_f32_16x16x32_bf16(a[bd], bl, acc[bd][tn], 0, 0, 0);
            }
        }
    }
#pragma unroll
    for (int bd = 0; bd < 2; bd++)
#pragma unroll
        for (int tn = 0; tn < 8; tn++)
#pragma unroll
            for (int r = 0; r < 4; r++)
                t0[w][bd * 16 + lq + r][tn * 16 + lr] = f2bf(fmaxf(acc[bd][tn][r] + b0v[tn], 0.f));

    // ---- layer 2: t0 @ W1 ----
#pragma unroll
    for (int bd = 0; bd < 2; bd++)
#pragma unroll
        for (int tn = 0; tn < 8; tn++) acc[bd][tn] = (f32x4){0.f, 0.f, 0.f, 0.f};
#pragma unroll
    for (int kc = 0; kc < 4; kc++) {
        short8 a[2];
#pragma unroll
        for (int bd = 0; bd < 2; bd++)
            a[bd] = *(const short8*)&t0[w][bd * 16 + lr][kc * 32 + lk];
#pragma unroll
        for (int tn = 0; tn < 8; tn++) {
            size_t fo = (size_t)(((kc * 8 + tn) * 64 + L)) * 8;
            short8 bh = *(const short8*)(w1hi + fo);
            short8 bl = *(const short8*)(w1lo + fo);
#pragma unroll
            for (int bd = 0; bd < 2; bd++) {
                acc[bd][tn] = __builtin_amdgcn_mfma_f32_16x16x32_bf16(a[bd], bh, acc[bd][tn], 0, 0, 0);
                acc[bd][tn] = __builtin_amdgcn_mfma_f32_16x16x32_bf16(a[bd], bl, acc[bd][tn], 0, 0, 0);
            }
        }
    }
    float invs[2][4];
#pragma unroll
    for (int bd = 0; bd < 2; bd++)
#pragma unroll
        for (int r = 0; r < 4; r++) {
            int grow = m0 + bd * 16 + lq + r; if (grow >= M) grow = M - 1;
            invs[bd][r] = inv_s[grow];
        }
#pragma unroll
    for (int bd = 0; bd < 2; bd++)
#pragma unroll
        for (int tn = 0; tn < 8; tn++)
#pragma unroll
            for (int r = 0; r < 4; r++)
                t0[w][bd * 16 + lq + r][tn * 16 + lr] =
                    f2bf(fmaxf(acc[bd][tn][r] + b1v[tn], 0.f) * invs[bd][r]);
    // X -> fp8 store (8 channels = 8 B per lane-chunk, coalesced)
#pragma unroll
    for (int q = 0; q < 8; q++) {
        int s = q * 64 + L;
        int row = s >> 4, c0 = (s & 15) * 8;
        int grow = m0 + row;
        if (grow < M) {
            const unsigned short* sp = &t0[w][row][c0];
            uint2 v;
            v.x = pk_fp8x4(bf2f(sp[0]), bf2f(sp[1]), bf2f(sp[2]), bf2f(sp[3]));
            v.y = pk_fp8x4(bf2f(sp[4]), bf2f(sp[5]), bf2f(sp[6]), bf2f(sp[7]));
            *(uint2*)(x8 + (size_t)grow * 128 + c0) = v;
        }
    }
}

// ---------- MLP step 1 (reads h16 bf16 global; x out: fp8) -------------------
__global__ __launch_bounds__(256) void k_mlp(
    const unsigned short* __restrict__ A16, const unsigned short* __restrict__ w0hi,
    const unsigned short* __restrict__ w0lo, const unsigned short* __restrict__ w1hi,
    const unsigned short* __restrict__ w1lo, const float* __restrict__ b0,
    const float* __restrict__ b1, const float* __restrict__ inv_s,
    unsigned char* __restrict__ x8, int M)
{
    __shared__ __align__(16) unsigned short t1[4][32][136];   // per-wave, barrier-free
    int t = threadIdx.x, w = t >> 6, L = t & 63;
    int m0 = blockIdx.x * 128 + w * 32;
    int lr = L & 15, lk = (L >> 4) * 8, lq = (L >> 4) * 4;

    float b0v[8], b1v[8];
#pragma unroll
    for (int tn = 0; tn < 8; tn++) { b0v[tn] = b0[tn * 16 + lr]; b1v[tn] = b1[tn * 16 + lr]; }

    f32x4 acc[2][8];
#pragma unroll
    for (int bd = 0; bd < 2; bd++)
#pragma unroll
        for (int tn = 0; tn < 8; tn++) acc[bd][tn] = (f32x4){0.f, 0.f, 0.f, 0.f};

#pragma unroll
    for (int kc = 0; kc < 4; kc++) {
        short8 a[2];
#pragma unroll
        for (int bd = 0; bd < 2; bd++) {
            int grow = m0 + bd * 16 + lr; if (grow >= M) grow = M - 1;
            a[bd] = *(const short8*)(A16 + (size_t)grow * 128 + kc * 32 + lk);
        }
#pragma unroll
        for (int tn = 0; tn < 8; tn++) {
            size_t fo = (size_t)(((kc * 8 + tn) * 64 + L)) * 8;
            short8 bh = *(const short8*)(w0hi + fo);
            short8 bl = *(const short8*)(w0lo + fo);
#pragma unroll
            for (int bd = 0; bd < 2; bd++) {
                acc[bd][tn] = __builtin_amdgcn_mfma_f32_16x16x32_bf16(a[bd], bh, acc[bd][tn], 0, 0, 0);
                acc[bd][tn] = __builtin_amdgcn_mfma_f32_16x16x32_bf16(a[bd], bl, acc[bd][tn], 0, 0, 0);
            }
        }
    }
#pragma unroll
    for (int bd = 0; bd < 2; bd++)
#pragma unroll
        for (int tn = 0; tn < 8; tn++)
#pragma unroll
            for (int r = 0; r < 4; r++)
                t1[w][bd * 16 + lq + r][tn * 16 + lr] = f2bf(fmaxf(acc[bd][tn][r] + b0v[tn], 0.f));

    f32x4 acc2[2][8];
#pragma unroll
    for (int bd = 0; bd < 2; bd++)
#pragma unroll
        for (int tn = 0; tn < 8; tn++) acc2[bd][tn] = (f32x4){0.f, 0.f, 0.f, 0.f};
#pragma unroll
    for (int kc = 0; kc < 4; kc++) {
        short8 a[2];
#pragma unroll
        for (int bd = 0; bd < 2; bd++)
            a[bd] = *(const short8*)&t1[w][bd * 16 + lr][kc * 32 + lk];
#pragma unroll
        for (int tn = 0; tn < 8; tn++) {
            size_t fo = (size_t)(((kc * 8 + tn) * 64 + L)) * 8;
            short8 bh = *(const short8*)(w1hi + fo);
            short8 bl = *(const short8*)(w1lo + fo);
#pragma unroll
            for (int bd = 0; bd < 2; bd++) {
                acc2[bd][tn] = __builtin_amdgcn_mfma_f32_16x16x32_bf16(a[bd], bh, acc2[bd][tn], 0, 0, 0);
                acc2[bd][tn] = __builtin_amdgcn_mfma_f32_16x16x32_bf16(a[bd], bl, acc2[bd][tn], 0, 0, 0);
            }
        }
    }
    float invs[2][4];
#pragma unroll
    for (int bd = 0; bd < 2; bd++)
#pragma unroll
        for (int r = 0; r < 4; r++) {
            int grow = m0 + bd * 16 + lq + r; if (grow >= M) grow = M - 1;
            invs[bd][r] = inv_s[grow];
        }
#pragma unroll
    for (int bd = 0; bd < 2; bd++)
#pragma unroll
        for (int tn = 0; tn < 8; tn++)
#pragma unroll
            for (int r = 0; r < 4; r++)
                t1[w][bd * 16 + lq + r][tn * 16 + lr] =
                    f2bf(fmaxf(acc2[bd][tn][r] + b1v[tn], 0.f) * invs[bd][r]);
#pragma unroll
    for (int q = 0; q < 8; q++) {
        int s = q * 64 + L;
        int row = s >> 4, c0 = (s & 15) * 8;
        int grow = m0 + row;
        if (grow < M) {
            const unsigned short* sp = &t1[w][row][c0];
            uint2 v;
            v.x = pk_fp8x4(bf2f(sp[0]), bf2f(sp[1]), bf2f(sp[2]), bf2f(sp[3]));
            v.y = pk_fp8x4(bf2f(sp[4]), bf2f(sp[5]), bf2f(sp[6]), bf2f(sp[7]));
            *(uint2*)(x8 + (size_t)grow * 128 + c0) = v;
        }
    }
}

// ---------- gather core (fp8 table): full batches + ONE masked batch ---------
__device__ __forceinline__ float2 agg_gather8(const unsigned char* __restrict__ x8,
                                              const int* __restrict__ edge_src,
                                              int node, int L, int beg, int end)
{
    unsigned short su = *(const unsigned short*)(x8 + (size_t)node * 128 + 2 * L);
    float2 acc;
    acc.x = __builtin_amdgcn_cvt_f32_fp8((int)su, 0);    // self loop
    acc.y = __builtin_amdgcn_cvt_f32_fp8((int)su, 1);

    int j = beg;
    for (; j + 8 <= end; j += 8) {
        unsigned short u[8];
#pragma unroll
        for (int q = 0; q < 8; q++)
            u[q] = *(const unsigned short*)(x8 + (size_t)edge_src[j + q] * 128 + 2 * L);
#pragma unroll
        for (int q = 0; q < 8; q++) {
            acc.x += __builtin_amdgcn_cvt_f32_fp8((int)u[q], 0);
            acc.y += __builtin_amdgcn_cvt_f32_fp8((int)u[q], 1);
        }
    }
    if (j < end) {                                  // masked parallel remainder
        int last = end - 1;
        unsigned short u[8];
#pragma unroll
        for (int q = 0; q < 8; q++) {
            int jj = j + q; if (jj > last) jj = last;
            u[q] = *(const unsigned short*)(x8 + (size_t)edge_src[jj] * 128 + 2 * L);
        }
#pragma unroll
        for (int q = 0; q < 8; q++) {
            float a = __builtin_amdgcn_cvt_f32_fp8((int)u[q], 0);
            float b = __builtin_amdgcn_cvt_f32_fp8((int)u[q], 1);
            if (j + q <= last) { acc.x += a; acc.y += b; }   // wave-uniform pred
        }
    }
    return acc;
}

// ---------- agg step 0: 1 wave/node, writes h16 ------------------------------
__global__ __launch_bounds__(256) void k_agg_ln(
    const unsigned char* __restrict__ x8, const int* __restrict__ row_start,
    const int* __restrict__ edge_src, const float* __restrict__ inv_r,
    const float* __restrict__ ln_scale, const float* __restrict__ ln_offset,
    unsigned short* __restrict__ h16)
{
    int node = __builtin_amdgcn_readfirstlane(blockIdx.x * 4 + (threadIdx.x >> 6));
    int L = threadIdx.x & 63;
    const unsigned int* h32 = (const unsigned int*)h16;

    int beg = row_start[node], end = row_start[node + 1];
    float2 acc = agg_gather8(x8, edge_src, node, L, beg, end);

    float ir = inv_r[node];
    unsigned int hu = h32[(size_t)node * 64 + L];
    float y0 = acc.x * ir + __uint_as_float(hu << 16);
    float y1 = acc.y * ir + __uint_as_float(hu & 0xffff0000u);

    float s1 = y0 + y1, s2 = y0 * y0 + y1 * y1;
#pragma unroll
    for (int off = 32; off > 0; off >>= 1) {
        s1 += __shfl_xor(s1, off, 64);
        s2 += __shfl_xor(s2, off, 64);
    }
    float mu = s1 * (1.f / 128.f);
    float var = fmaxf(s2 * (1.f / 128.f) - mu * mu, 0.f);
    float rstd = rsqrtf(var + 1e-5f);
    float2 sc = *(const float2*)&ln_scale[L * 2];
    float2 of = *(const float2*)&ln_offset[L * 2];
    float ox = (y0 - mu) * rstd * sc.x + of.x;
    float oy = (y1 - mu) * rstd * sc.y + of.y;
    ((unsigned int*)h16)[(size_t)node * 64 + L] =
        (unsigned int)f2bf(ox) | ((unsigned int)f2bf(oy) << 16);
}

// ---------- agg step 1 + pooling: no h16 write -------------------------------
__global__ __launch_bounds__(256) void k_agg_pool(
    const unsigned char* __restrict__ x8, const int* __restrict__ row_start,
    const int* __restrict__ edge_src, const float* __restrict__ inv_r,
    const float* __restrict__ ln_scale, const float* __restrict__ ln_offset,
    const unsigned short* __restrict__ h16, float* __restrict__ poolpart)
{
    __shared__ float2 part[4][64];
    int w = threadIdx.x >> 6, L = threadIdx.x & 63;
    int node = __builtin_amdgcn_readfirstlane(blockIdx.x * 4 + w);
    const unsigned int* h32 = (const unsigned int*)h16;

    int beg = row_start[node], end = row_start[node + 1];
    float2 acc = agg_gather8(x8, edge_src, node, L, beg, end);

    float ir = inv_r[node];
    unsigned int hu = h32[(size_t)node * 64 + L];
    float y0 = acc.x * ir + __uint_as_float(hu << 16);
    float y1 = acc.y * ir + __uint_as_float(hu & 0xffff0000u);

    float s1 = y0 + y1, s2 = y0 * y0 + y1 * y1;
#pragma unroll
    for (int off = 32; off > 0; off >>= 1) {
        s1 += __shfl_xor(s1, off, 64);
        s2 += __shfl_xor(s2, off, 64);
    }
    float mu = s1 * (1.f / 128.f);
    float var = fmaxf(s2 * (1.f / 128.f) - mu * mu, 0.f);
    float rstd = rsqrtf(var + 1e-5f);
    float2 sc = *(const float2*)&ln_scale[L * 2];
    float2 of = *(const float2*)&ln_offset[L * 2];
    float2 o;
    o.x = (y0 - mu) * rstd * sc.x + of.x;
    o.y = (y1 - mu) * rstd * sc.y + of.y;
    part[w][L] = o;
    __syncthreads();
    if (w == 0) {
        float2 p0 = part[0][L], p1 = part[1][L], p2 = part[2][L], p3 = part[3][L];
        float2 s;
        s.x = (p0.x + p1.x) + (p2.x + p3.x);
        s.y = (p0.y + p1.y) + (p2.y + p3.y);
        *(float2*)&poolpart[(size_t)blockIdx.x * 128 + L * 2] = s;
    }
}

// ---------- pool reduce level 1: 25000 partial rows -> 1000 ----------
__global__ __launch_bounds__(128) void k_pool2(const float* __restrict__ poolpart,
                                               float* __restrict__ poolpart2) {
    int b = blockIdx.x, col = threadIdx.x;
    const float* pg = poolpart + ((size_t)b * 25) * 128;
    float s = 0.f;
#pragma unroll
    for (int k = 0; k < 25; k++) s += pg[k * 128 + col];
    poolpart2[(size_t)b * 128 + col] = s;
}

// ---------- pool reduce level 2 + decode ----------
__global__ __launch_bounds__(128) void k_pool3(const float* __restrict__ poolpart2,
                                               const float* __restrict__ dec_w,
                                               const float* __restrict__ dec_b,
                                               float* __restrict__ out) {
    int g = blockIdx.x, col = threadIdx.x;
    const float* pg = poolpart2 + (size_t)g * 10 * 128;
    float s = 0.f;
#pragma unroll
    for (int c = 0; c < 10; c++) s += pg[c * 128 + col];
    s = s * (1.f / (float)NPG) * dec_w[col];
    __shared__ float ws[2];
#pragma unroll
    for (int off = 32; off > 0; off >>= 1) s += __shfl_down(s, off, 64);
    if ((col & 63) == 0) ws[col >> 6] = s;
    __syncthreads();
    if (col == 0) out[g] = ws[0] + ws[1] + dec_b[0];
}

extern "C" void kernel_launch(void* const* d_in, const int* in_sizes, int n_in,
                              void* d_out, int out_size, void* d_ws, size_t ws_size,
                              hipStream_t stream) {
    (void)in_sizes; (void)n_in; (void)out_size; (void)ws_size;
    const float* nodes     = (const float*)d_in[0];
    const int*   senders   = (const int*)d_in[1];
    const int*   receivers = (const int*)d_in[2];
    const float* embed_w   = (const float*)d_in[4];
    const float* embed_b   = (const float*)d_in[5];
    const float* mlp_w     = (const float*)d_in[6];
    const float* mlp_b     = (const float*)d_in[7];
    const float* ln_scale  = (const float*)d_in[8];
    const float* ln_offset = (const float*)d_in[9];
    const float* dec_w     = (const float*)d_in[10];
    const float* dec_b     = (const float*)d_in[11];
    float* out = (float*)d_out;

    const int N = N_NODES;
    const int WF_TOTAL = 8192 + 4 * 16384;          // frag elements (shorts)
    const size_t PART_TOTAL = (size_t)NPART * NSLICE * PSIZE;  // 6.4M entries

    char* p = (char*)d_ws;
    auto alloc = [&](size_t bytes) -> void* {
        void* r = (void*)p;
        p += (bytes + 255) & ~(size_t)255;
        return r;
    };
    unsigned short* h16      = (unsigned short*)alloc((size_t)N * 128 * 2);
    unsigned char*  x8       = (unsigned char*)alloc((size_t)N * 128);
    int*            edge_src = (int*)alloc((size_t)N_EDGES * 4);
    unsigned short* ps16     = (unsigned short*)alloc(PART_TOTAL * 2);
    unsigned short* pr16     = (unsigned short*)alloc(PART_TOTAL * 2);
    int*            deg_r    = (int*)alloc((size_t)N * 4);
    float*          inv_s    = (float*)alloc((size_t)N * 4);
    float*          inv_r    = (float*)alloc((size_t)N * 4);
    int*            row_start= (int*)alloc((size_t)(N + 1) * 4);
    int*            blocksums= (int*)alloc((size_t)SCAN_NB * 4);
    unsigned short* wfhi     = (unsigned short*)alloc((size_t)WF_TOTAL * 2);
    unsigned short* wflo     = (unsigned short*)alloc((size_t)WF_TOTAL * 2);
    float*          poolpart = (float*)alloc((size_t)(N / 4) * 128 * 4);
    float*          poolpart2= (float*)alloc((size_t)1000 * 128 * 4);

    hipMemsetAsync(blocksums, 0, (size_t)SCAN_NB * 4, stream);
    k_wprep<<<(WF_TOTAL + 255) / 256, 256, 0, stream>>>(embed_w, mlp_w, wfhi, wflo);

    // graph prep — no global fp32 atomics (391 int atomics for blocksums only)
    k_hist2<<<NPART * NSLICE, 1024, 0, stream>>>(senders, receivers, ps16, pr16);
    k_scan_slices<<<(N + 255) / 256, 256, 0, stream>>>(ps16, pr16, deg_r, inv_s, inv_r, blocksums);
    k_scan_apply<<<SCAN_NB, 256, 0, stream>>>(deg_r, blocksums, row_start, N);
    k_fill2<<<NPART * NSLICE, 1024, 0, stream>>>(senders, receivers, pr16, row_start, edge_src);

    int mblocks = (N + 127) / 128;
    const unsigned short* wehi = wfhi, *welo = wflo;
    const unsigned short* w0hi[2] = { wfhi + 8192,             wfhi + 8192 + 2 * 16384 };
    const unsigned short* w0lo[2] = { wflo + 8192,             wflo + 8192 + 2 * 16384 };
    const unsigned short* w1hi[2] = { wfhi + 8192 + 16384,     wfhi + 8192 + 3 * 16384 };
    const unsigned short* w1lo[2] = { wflo + 8192 + 16384,     wflo + 8192 + 3 * 16384 };

    // step 0: fused embed + MLP, then agg+LN into h16
    k_embed_mlp<<<mblocks, 256, 0, stream>>>(nodes, wehi, welo, embed_b,
                                             w0hi[0], w0lo[0], w1hi[0], w1lo[0],
                                             mlp_b, mlp_b + 128, inv_s, h16, x8, N);
    k_agg_ln<<<N / 4, 256, 0, stream>>>(x8, row_start, edge_src, inv_r,
                                        ln_scale, ln_offset, h16);
    // step 1: MLP, then agg+LN fused with pooling (no h16 write)
    k_mlp<<<mblocks, 256, 0, stream>>>(h16, w0hi[1], w0lo[1], w1hi[1], w1lo[1],
                                       mlp_b + 256, mlp_b + 384, inv_s, x8, N);
    k_agg_pool<<<N / 4, 256, 0, stream>>>(x8, row_start, edge_src, inv_r,
                                          ln_scale + 128, ln_offset + 128, h16, poolpart);

    k_pool2<<<1000, 128, 0, stream>>>(poolpart, poolpart2);
    k_pool3<<<N_GRAPH, 128, 0, stream>>>(poolpart2, dec_w, dec_b, out);
}